// Round 7
// baseline (294.060 us; speedup 1.0000x reference)
//
#include <hip/hip_runtime.h>
#include <hip/hip_bf16.h>

// Problem constants (from reference)
#define NB   64          // graphs
#define NPG  2048        // nodes per graph
#define NN   (NB*NPG)    // 131072 total nodes
#define EPG  32768       // edges per graph
#define EE   (NB*EPG)    // 2097152 edges
#define DD   32          // feature dim
#define KK   1024        // kept nodes per graph (ratio 0.5)

#define QCAP 2560        // packed-edge region capacity per (s,g,q); mean 2048, +13 sigma

typedef unsigned long long u64;
typedef unsigned int u32;

// ---------------------------------------------------------------------------
// K1 (R23, R24: int4 loads): qscatter — 4-bucket (graph-quarter) edge
// partition. 256 blocks: g = b&63 (XCD affinity), s = b>>6, 8192 edges each.
// Positions via ballot/popc wave ranks + LDS cross-wave scan — fully
// DETERMINISTIC, zero atomics. Each (s,g,q) owns a fixed QCAP region.
// Edge packed to 4B: (src_local<<9)|(dst_local&511); q = dl>>9 implied.
// ---------------------------------------------------------------------------
__global__ __launch_bounds__(1024) void qscatter_kernel(
    const int* __restrict__ src, const int* __restrict__ dst,
    int* __restrict__ qcnt, int* __restrict__ packed)
{
    __shared__ int wcnt[16][4];
    __shared__ int wbase[16][4];
    int b = blockIdx.x, t = threadIdx.x;
    int g = b & 63, s = b >> 6;
    int w = t >> 6, lane = t & 63;
    const int ebase = g * EPG + s * 8192;
    const int nbase = g * NPG;
    u64 ltmask = (1ull << lane) - 1ull;

    int pk[8], qv[8], pos[8];
    int wq0 = 0, wq1 = 0, wq2 = 0, wq3 = 0;
#pragma unroll
    for (int r = 0; r < 2; r++) {
        int e = ebase + r * 4096 + t * 4;
        int4 sv = *(const int4*)(src + e);
        int4 dv = *(const int4*)(dst + e);
        const int* sp = &sv.x; const int* dp = &dv.x;
#pragma unroll
        for (int m = 0; m < 4; m++) {
            int idx = r * 4 + m;
            int sl = sp[m] - nbase;       // 0..2047
            int dl = dp[m] - nbase;       // 0..2047
            int q  = dl >> 9;             // quarter 0..3
            pk[idx] = (sl << 9) | (dl & 511);
            qv[idx] = q;
            u64 b0 = __ballot(q == 0);
            u64 b1 = __ballot(q == 1);
            u64 b2 = __ballot(q == 2);
            u64 b3 = __ballot(q == 3);
            int rk = (q == 0) ? wq0 + __popcll(b0 & ltmask)
                   : (q == 1) ? wq1 + __popcll(b1 & ltmask)
                   : (q == 2) ? wq2 + __popcll(b2 & ltmask)
                              : wq3 + __popcll(b3 & ltmask);
            pos[idx] = rk;
            wq0 += __popcll(b0); wq1 += __popcll(b1);
            wq2 += __popcll(b2); wq3 += __popcll(b3);
        }
    }
    if (lane == 0) {
        wcnt[w][0] = wq0; wcnt[w][1] = wq1;
        wcnt[w][2] = wq2; wcnt[w][3] = wq3;
    }
    __syncthreads();
    if (t < 4) {                          // serial 16-wave scan per quarter
        int run = 0;
        for (int ww = 0; ww < 16; ww++) { wbase[ww][t] = run; run += wcnt[ww][t]; }
        qcnt[((s * 64 + g) << 2) + t] = run;
    }
    __syncthreads();
    const int rbase = (s * 64 + g) << 2;
#pragma unroll
    for (int r = 0; r < 8; r++) {
        int q = qv[r];
        packed[(size_t)(rbase + q) * QCAP + wbase[w][q] + pos[r]] = pk[r];
    }
}

// ---------------------------------------------------------------------------
// K2 (R23; R26 lane-per-dim): agg2 — LDS fixed-point scatter-add. One block
// per (g = b&63 [XCD affinity], q = b>>6): 512-node quarter slab as int32
// LDS accumulator (64KB).
// R26: wave = 2 edges x 32 dim-lanes (was 16 edges x 4 subs x 8 dims).
// Lane d of each half-wave issues ONE atomic at (dl<<5)|(d^(dl&31)).
// XOR-with-constant permutes the 32 banks -> each half-wave hits every bank
// exactly once -> exactly 2 lanes/bank per atomic instr = conflict-FREE
// (m136: 2-way is 1.02x). Old form: 16 random edges x 4 subs -> bank
// max-load ~4-5 -> ~1.6-1.9x serialization on 67M atomics. Also: x-row
// gather is now one coalesced 128B segment per half-wave; pkv is a 32-lane
// broadcast. Same atomic TERM SET, same layout, int adds commute -> agg
// bit-identical -> downstream bit-identical, replay-deterministic.
// Overflow: |sum| <= ~45*5*2^22 ~ 9.4e8 < 2^31.
// ---------------------------------------------------------------------------
__global__ __launch_bounds__(1024) void agg2_kernel(
    const float* __restrict__ x,
    const int* __restrict__ qcnt, const int* __restrict__ packed,
    float* __restrict__ agg)
{
    __shared__ int acc[512 * DD];        // 65536 B
    int b = blockIdx.x, t = threadIdx.x;
    int g = b & 63, q = b >> 6;
    for (int i = t; i < 512 * DD; i += 1024) acc[i] = 0;
    __syncthreads();

    const float SCALE = 4194304.0f;      // 2^22
    const float* xg = x + (size_t)g * NPG * DD;
    int d    = t & 31;                   // dim lane 0..31
    int slot = t >> 5;                   // edge slot 0..31 (2 per wave)

    for (int s = 0; s < 4; s++) {
        int n = qcnt[((s * 64 + g) << 2) + q];
        const int* pb = packed + (size_t)(((s * 64 + g) << 2) + q) * QCAP;
        for (int i = slot; i < n; i += 32) {
            int pkv = pb[i];             // 32 lanes share -> broadcast
            int dl  = pkv & 511;         // local row in quarter slab
            int sl  = pkv >> 9;          // src node 0..2047
            float v = xg[sl * DD + d];   // coalesced 128B per half-wave
            atomicAdd(&acc[(dl << 5) | (d ^ (dl & 31))],
                      __float2int_rn(v * SCALE));
        }
    }
    __syncthreads();

    const float ISCALE = 2.38418579101562e-07f;  // 2^-22
    float* ao = agg + ((size_t)g * NPG + (size_t)q * 512) * DD;
    for (int i = t; i < 512 * DD; i += 1024) {   // coalesced stores, swz reads
        int row = i >> 5, dd = i & 31;
        ao[i] = (float)acc[(row << 5) | (dd ^ (row & 31))] * ISCALE;
    }
}

// ---------------------------------------------------------------------------
// K2b: per-node score = <x2, y2> / sqrt(32). fp32 W in LDS (ds_read_b128,
// wave-uniform address -> broadcast, conflict-free). R=2 node-pairing
// (i, i+NN/2) + 2-way d-split — FINAL form, ~36us. Measured tree: beats
// bf16-W (R13), global-W (R7), launch-bounds caps (R10), float2 SLP (R16),
// forced v_pk_fma_f32 (R20: VALU saved but ds_read latency exposed, 36->44),
// scalar-W one-node-per-thread (R25: 128-float live set -> spill/remat
// churn, 36->115us REGRESSION, reverted). ESTABLISHED: this register
// blocking (4-float acc blocks, 2 threads/node) is the sweet spot; score
// must stay fp32-accurate; only summation-order changes are safe.
// ---------------------------------------------------------------------------
__global__ __launch_bounds__(256) void score_kernel(
    const float* __restrict__ x, const float* __restrict__ agg,
    const float* __restrict__ Wr1, const float* __restrict__ Wl1, const float* __restrict__ b1,
    const float* __restrict__ Wr2, const float* __restrict__ Wl2, const float* __restrict__ b2,
    float* __restrict__ score)
{
    __shared__ float4 sWr1[DD*DD/4], sWl1[DD*DD/4], sWr2[DD*DD/4], sWl2[DD*DD/4];
    __shared__ float sb1[DD], sb2[DD];
    __shared__ float2 part[128];
    {
        int t = threadIdx.x;             // 256 threads, 256 float4 per matrix
        sWr1[t] = ((const float4*)Wr1)[t];
        sWl1[t] = ((const float4*)Wl1)[t];
        sWr2[t] = ((const float4*)Wr2)[t];
        sWl2[t] = ((const float4*)Wl2)[t];
        if (t < DD) { sb1[t] = b1[t]; sb2[t] = b2[t]; }
    }
    __syncthreads();

    int lane = threadIdx.x & 127;
    int half = threadIdx.x >> 7;                 // 0: d0 0-3, 1: d0 4-7
    int i0 = blockIdx.x * 128 + lane;            // 0 .. NN/2-1
    int i1 = i0 + NN/2;                          // second dense stream

    float xv0[DD], av0[DD], xv1[DD], av1[DD];
    {
        const float4* xp0 = (const float4*)(x + (long long)i0 * DD);
        const float4* ap0 = (const float4*)(agg + (long long)i0 * DD);
        const float4* xp1 = (const float4*)(x + (long long)i1 * DD);
        const float4* ap1 = (const float4*)(agg + (long long)i1 * DD);
#pragma unroll
        for (int q = 0; q < 8; q++) {
            float4 v0 = xp0[q]; xv0[4*q]=v0.x; xv0[4*q+1]=v0.y; xv0[4*q+2]=v0.z; xv0[4*q+3]=v0.w;
            float4 w0 = ap0[q]; av0[4*q]=w0.x; av0[4*q+1]=w0.y; av0[4*q+2]=w0.z; av0[4*q+3]=w0.w;
            float4 v1 = xp1[q]; xv1[4*q]=v1.x; xv1[4*q+1]=v1.y; xv1[4*q+2]=v1.z; xv1[4*q+3]=v1.w;
            float4 w1 = ap1[q]; av1[4*q]=w1.x; av1[4*q+1]=w1.y; av1[4*q+2]=w1.z; av1[4*q+3]=w1.w;
        }
    }

    float sc0 = 0.f, sc1 = 0.f;
    int dbase = half * 4;
    for (int dd = 0; dd < 4; dd++) {             // this thread's 4 d0-blocks
        int d0 = dbase + dd;
        float a0[4], q0[4], a1[4], q1[4];
#pragma unroll
        for (int j = 0; j < 4; j++) {
            a0[j] = sb1[4*d0+j]; q0[j] = sb2[4*d0+j];
            a1[j] = sb1[4*d0+j]; q1[j] = sb2[4*d0+j];
        }
#pragma unroll
        for (int k = 0; k < DD; k++) {
            float4 wr1 = sWr1[k*8 + d0];
            float4 wl1 = sWl1[k*8 + d0];
            float4 wr2 = sWr2[k*8 + d0];
            float4 wl2 = sWl2[k*8 + d0];
            const float* r1 = &wr1.x; const float* l1 = &wl1.x;
            const float* r2 = &wr2.x; const float* l2 = &wl2.x;
            float xk0 = xv0[k], ak0 = av0[k];
            float xk1 = xv1[k], ak1 = av1[k];
#pragma unroll
            for (int j = 0; j < 4; j++) {
                a0[j] += xk0 * r1[j];   // per-d chain order == round 8
                a0[j] += ak0 * l1[j];
                q0[j] += xk0 * r2[j];
                q0[j] += ak0 * l2[j];
                a1[j] += xk1 * r1[j];
                a1[j] += ak1 * l1[j];
                q1[j] += xk1 * r2[j];
                q1[j] += ak1 * l2[j];
            }
        }
#pragma unroll
        for (int j = 0; j < 4; j++) { sc0 += a0[j] * q0[j]; sc1 += a1[j] * q1[j]; }
    }

    if (half) { part[lane].x = sc0; part[lane].y = sc1; }
    __syncthreads();
    if (!half) {
        float2 p = part[lane];
        score[i0] = (sc0 + p.x) * 0.17677669529663687f;   // 1/sqrt(32)
        score[i1] = (sc1 + p.y) * 0.17677669529663687f;
    }
}

// ---------------------------------------------------------------------------
// K3 (R24): per-graph top-K bitonic sort, register/shfl accelerated.
// Mapping: wave w, lane ln owns elements e0 = w*128+ln, e1 = e0+64.
// j<=32 intra-wave (__shfl_xor); j==64 intra-thread; only j>=128 uses LDS.
// 15 __syncthreads total (was 66). Unique keys -> total order -> ANY correct
// sort gives bit-identical output -> deterministic. Also initializes new_idx
// for ALL nodes (kept -> new label, dropped -> -1).
// ---------------------------------------------------------------------------
__device__ __forceinline__ u64 shfl_xor_u64(u64 v, int j) {
    u32 lo = (u32)v, hi = (u32)(v >> 32);
    lo = (u32)__shfl_xor((int)lo, j, 64);
    hi = (u32)__shfl_xor((int)hi, j, 64);
    return ((u64)hi << 32) | lo;
}

__device__ __forceinline__ void reg_step(u64& v, int e, int j, int k) {
    u64 vp = shfl_xor_u64(v, j);
    bool upper   = (e & j) != 0;
    bool asc     = (e & k) == 0;
    bool takemax = (upper == asc);
    bool gt      = v > vp;
    v = (gt == takemax) ? v : vp;
}

__global__ __launch_bounds__(1024) void topk_kernel(
    const float* __restrict__ score,
    int* __restrict__ perm_int, int* __restrict__ new_idx,
    float* __restrict__ out_perm,
    float* __restrict__ out_batch,
    float* __restrict__ out_score)
{
    __shared__ u64 keys[NPG];
    int b = blockIdx.x;
    int t = threadIdx.x;
    const float* s = score + (long long)b * NPG;
    int w = t >> 6, ln = t & 63;
    int e0 = w * 128 + ln, e1 = e0 + 64;

    u64 k0, k1;
    {
        u32 u = __float_as_uint(s[e0]);
        u32 h = (u & 0x80000000u) ? u : ~(u | 0x80000000u);
        k0 = ((u64)h << 32) | (u32)e0;
        u = __float_as_uint(s[e1]);
        h = (u & 0x80000000u) ? u : ~(u | 0x80000000u);
        k1 = ((u64)h << 32) | (u32)e1;
    }

    // levels k = 2..128: fully in-register, no barriers
    for (int k = 2; k <= 128; k <<= 1) {
        for (int j = k >> 1; j >= 1; j >>= 1) {
            if (j == 64) {
                bool asc = (e0 & k) == 0;
                u64 mx = (k0 > k1) ? k0 : k1;
                u64 mn = (k0 > k1) ? k1 : k0;
                k0 = asc ? mn : mx;
                k1 = asc ? mx : mn;
            } else {
                reg_step(k0, e0, j, k);
                reg_step(k1, e1, j, k);
            }
        }
    }

    // levels k = 256..2048: LDS for j>=128, registers below
    for (int k = 256; k <= NPG; k <<= 1) {
        keys[e0] = k0; keys[e1] = k1;
        __syncthreads();
        for (int j = k >> 1; j >= 128; j >>= 1) {
            int i = ((t & ~(j - 1)) << 1) | (t & (j - 1));
            int l = i | j;
            u64 a = keys[i], c = keys[l];
            bool up = ((i & k) == 0);
            if ((a > c) == up) { keys[i] = c; keys[l] = a; }
            __syncthreads();
        }
        k0 = keys[e0]; k1 = keys[e1];
        for (int j = 64; j >= 1; j >>= 1) {
            if (j == 64) {
                bool asc = (e0 & k) == 0;
                u64 mx = (k0 > k1) ? k0 : k1;
                u64 mn = (k0 > k1) ? k1 : k0;
                k0 = asc ? mn : mx;
                k1 = asc ? mx : mn;
            } else {
                reg_step(k0, e0, j, k);
                reg_step(k1, e1, j, k);
            }
        }
    }

    keys[e0] = k0; keys[e1] = k1;
    __syncthreads();

    // kept half: ranks 0..KK-1 (thread t owns rank t)
    u64 kk = keys[t];
    int idx = (int)(u32)(kk & 0xFFFFFFFFu);
    int g = b * NPG + idx;
    int o = b * KK + t;
    perm_int[o] = g;
    new_idx[g] = o;
    out_perm[o]  = (float)g;
    out_batch[o] = (float)b;
    out_score[o] = s[idx];

    // dropped half: ranks KK..NPG-1 -> new_idx = -1 (replaces memset)
    u64 kd = keys[t + KK];
    int idxd = (int)(u32)(kd & 0xFFFFFFFFu);
    new_idx[b * NPG + idxd] = -1;
}

// ---------------------------------------------------------------------------
// K4: x5 = x[g] + score[g] * (x[g]@Wr3 + agg[g]@Wl3 + b3), kept nodes only.
// d-split: two threads per node; fp32 W in LDS. NOTE: must complete before
// edge_kernel (agg aliases out_ei) — keep launches serial.
// ---------------------------------------------------------------------------
__global__ __launch_bounds__(256) void x5_kernel(
    const float* __restrict__ x, const float* __restrict__ agg,
    const float* __restrict__ Wr3, const float* __restrict__ Wl3, const float* __restrict__ b3,
    const int* __restrict__ perm_int, const float* __restrict__ score,
    float* __restrict__ out_x5)
{
    __shared__ float4 sWr[DD*DD/4], sWl[DD*DD/4];
    __shared__ float sb[DD];
    {
        int t = threadIdx.x;
        sWr[t] = ((const float4*)Wr3)[t];
        sWl[t] = ((const float4*)Wl3)[t];
        if (t < DD) sb[t] = b3[t];
    }
    __syncthreads();

    int lane = threadIdx.x & 127;
    int half = threadIdx.x >> 7;
    int i = blockIdx.x * 128 + lane;             // 0 .. NB*KK-1 (grid 512)
    int g = perm_int[i];
    float sc = score[g];

    float xv[DD], av[DD];
    {
        const float4* xp = (const float4*)(x + (long long)g * DD);
        const float4* ap = (const float4*)(agg + (long long)g * DD);
#pragma unroll
        for (int q = 0; q < 8; q++) {
            float4 v = xp[q]; xv[4*q]=v.x; xv[4*q+1]=v.y; xv[4*q+2]=v.z; xv[4*q+3]=v.w;
            float4 w = ap[q]; av[4*q]=w.x; av[4*q+1]=w.y; av[4*q+2]=w.z; av[4*q+3]=w.w;
        }
    }

    float* outp = out_x5 + (long long)i * DD;
    int dbase = half * 4;
    for (int dd = 0; dd < 4; dd++) {
        int d0 = dbase + dd;
        float a[4];
#pragma unroll
        for (int j = 0; j < 4; j++) a[j] = sb[4*d0+j];
#pragma unroll
        for (int k = 0; k < DD; k++) {
            float xk = xv[k], ak = av[k];
            float4 wr = sWr[k*8 + d0];
            float4 wl = sWl[k*8 + d0];
            const float* rp = &wr.x; const float* lp = &wl.x;
#pragma unroll
            for (int j = 0; j < 4; j++) {
                a[j] += xk * rp[j];
                a[j] += ak * lp[j];
            }
        }
#pragma unroll
        for (int j = 0; j < 4; j++) outp[4*d0+j] = xv[4*d0+j] + sc * a[j];
    }
}

// ---------------------------------------------------------------------------
// K5: filter_adj — relabel edges, mask dropped. 4 edges/thread, vectorized.
// Runs last; overwrites the agg (out_ei) scratch.
// ---------------------------------------------------------------------------
__global__ __launch_bounds__(256) void edge_kernel(
    const int* __restrict__ src, const int* __restrict__ dst,
    const float* __restrict__ edge_attr,
    const int* __restrict__ new_idx,
    float* __restrict__ out_ei,    // [2*EE]
    float* __restrict__ out_attr)  // [EE]
{
    int e = (blockIdx.x * 256 + threadIdx.x) * 4;
    if (e >= EE) return;
    int4 s4 = *(const int4*)(src + e);
    int4 d4 = *(const int4*)(dst + e);
    float4 at = *(const float4*)(edge_attr + e);

    int ns[4] = { new_idx[s4.x], new_idx[s4.y], new_idx[s4.z], new_idx[s4.w] };
    int nd[4] = { new_idx[d4.x], new_idx[d4.y], new_idx[d4.z], new_idx[d4.w] };
    float av[4] = { at.x, at.y, at.z, at.w };

    float4 os, od, oa;
    float* osp = &os.x; float* odp = &od.x; float* oap = &oa.x;
#pragma unroll
    for (int j = 0; j < 4; j++) {
        bool valid = (ns[j] >= 0) && (nd[j] >= 0);
        osp[j] = (float)(valid ? ns[j] : -1);
        odp[j] = (float)(valid ? nd[j] : -1);
        oap[j] = valid ? av[j] : 0.f;
    }
    *(float4*)(out_ei + e)      = os;
    *(float4*)(out_ei + EE + e) = od;
    *(float4*)(out_attr + e)    = oa;
}

// ---------------------------------------------------------------------------
extern "C" void kernel_launch(void* const* d_in, const int* in_sizes, int n_in,
                              void* d_out, int out_size, void* d_ws, size_t ws_size,
                              hipStream_t stream)
{
    const float* x     = (const float*)d_in[0];         // fp32 [N, D]
    const int*   src   = (const int*)d_in[1];           // edge_index[0]
    const int*   dst   = ((const int*)d_in[1]) + EE;    // edge_index[1]
    const float* eattr = (const float*)d_in[2];         // fp32 [E]
    // d_in[3] = batch (implied: node g belongs to graph g/NPG)
    const float* Wr1 = (const float*)d_in[4];
    const float* Wl1 = (const float*)d_in[5];
    const float* b1  = (const float*)d_in[6];
    const float* Wr2 = (const float*)d_in[7];
    const float* Wl2 = (const float*)d_in[8];
    const float* b2  = (const float*)d_in[9];
    const float* Wr3 = (const float*)d_in[10];
    const float* Wl3 = (const float*)d_in[11];
    const float* b3  = (const float*)d_in[12];

    // ---- workspace layout (~11.8 MiB)
    char* ws = (char*)d_ws;
    float* score    = (float*)(ws + 0);                                   // NN*4
    int*   perm_int = (int*)  (ws + (size_t)NN*4);                        // NB*KK*4
    int*   new_idx  = (int*)  (ws + (size_t)NN*4 + (size_t)NB*KK*4);      // NN*4
    int*   qcnt     = (int*)  (ws + (size_t)NN*8 + (size_t)NB*KK*4);      // 1024*4
    int*   packed   = (int*)  (ws + (size_t)NN*8 + (size_t)NB*KK*4 + 4096); // 1024*QCAP*4

    // ---- output layout: ONE flat fp32 buffer, reference return order
    float* out = (float*)d_out;
    float* out_x5    = out;                       // NB*KK*DD = 2097152
    float* out_ei    = out + (size_t)NB*KK*DD;    // 2*EE     = 4194304
    float* out_attr  = out_ei + (size_t)2*EE;     // EE       = 2097152
    float* out_batch = out_attr + (size_t)EE;     // NB*KK
    float* out_perm  = out_batch + (size_t)NB*KK; // NB*KK
    float* out_score = out_perm + (size_t)NB*KK;  // NB*KK

    // Scratch aliasing into dead output region (edge_kernel runs last):
    //   agg = NN*DD fp32 == out_ei region (exact fit)
    float* agg = out_ei;

    qscatter_kernel<<<256, 1024, 0, stream>>>(src, dst, qcnt, packed);

    agg2_kernel<<<256, 1024, 0, stream>>>(x, qcnt, packed, agg);

    score_kernel<<<NN/256, 256, 0, stream>>>(x, agg, Wr1, Wl1, b1, Wr2, Wl2, b2, score);

    topk_kernel<<<NB, 1024, 0, stream>>>(score, perm_int, new_idx,
                                         out_perm, out_batch, out_score);

    x5_kernel<<<(NB*KK)/128, 256, 0, stream>>>(x, agg, Wr3, Wl3, b3,
                                               perm_int, score, out_x5);

    edge_kernel<<<(EE/4)/256, 256, 0, stream>>>(src, dst, eattr, new_idx, out_ei, out_attr);
}

// Round 9
// 197.918 us; speedup vs baseline: 1.4858x; 1.4858x over previous
//
#include <hip/hip_runtime.h>
#include <hip/hip_bf16.h>

// Problem constants (from reference)
#define NB   64          // graphs
#define NPG  2048        // nodes per graph
#define NN   (NB*NPG)    // 131072 total nodes
#define EPG  32768       // edges per graph
#define EE   (NB*EPG)    // 2097152 edges
#define DD   32          // feature dim
#define KK   1024        // kept nodes per graph (ratio 0.5)

#define QCAP 2560        // packed-edge region capacity per (s,g,q); mean 2048, +13 sigma

typedef unsigned long long u64;
typedef unsigned int u32;

// ---------------------------------------------------------------------------
// K1 (R23, R24: int4 loads): qscatter — 4-bucket (graph-quarter) edge
// partition. 256 blocks: g = b&63 (XCD affinity), s = b>>6, 8192 edges each.
// Positions via ballot/popc wave ranks + LDS cross-wave scan — fully
// DETERMINISTIC, zero atomics. Each (s,g,q) owns a fixed QCAP region.
// Edge packed to 4B: (src_local<<9)|(dst_local&511); q = dl>>9 implied.
// ---------------------------------------------------------------------------
__global__ __launch_bounds__(1024) void qscatter_kernel(
    const int* __restrict__ src, const int* __restrict__ dst,
    int* __restrict__ qcnt, int* __restrict__ packed)
{
    __shared__ int wcnt[16][4];
    __shared__ int wbase[16][4];
    int b = blockIdx.x, t = threadIdx.x;
    int g = b & 63, s = b >> 6;
    int w = t >> 6, lane = t & 63;
    const int ebase = g * EPG + s * 8192;
    const int nbase = g * NPG;
    u64 ltmask = (1ull << lane) - 1ull;

    int pk[8], qv[8], pos[8];
    int wq0 = 0, wq1 = 0, wq2 = 0, wq3 = 0;
#pragma unroll
    for (int r = 0; r < 2; r++) {
        int e = ebase + r * 4096 + t * 4;
        int4 sv = *(const int4*)(src + e);
        int4 dv = *(const int4*)(dst + e);
        const int* sp = &sv.x; const int* dp = &dv.x;
#pragma unroll
        for (int m = 0; m < 4; m++) {
            int idx = r * 4 + m;
            int sl = sp[m] - nbase;       // 0..2047
            int dl = dp[m] - nbase;       // 0..2047
            int q  = dl >> 9;             // quarter 0..3
            pk[idx] = (sl << 9) | (dl & 511);
            qv[idx] = q;
            u64 b0 = __ballot(q == 0);
            u64 b1 = __ballot(q == 1);
            u64 b2 = __ballot(q == 2);
            u64 b3 = __ballot(q == 3);
            int rk = (q == 0) ? wq0 + __popcll(b0 & ltmask)
                   : (q == 1) ? wq1 + __popcll(b1 & ltmask)
                   : (q == 2) ? wq2 + __popcll(b2 & ltmask)
                              : wq3 + __popcll(b3 & ltmask);
            pos[idx] = rk;
            wq0 += __popcll(b0); wq1 += __popcll(b1);
            wq2 += __popcll(b2); wq3 += __popcll(b3);
        }
    }
    if (lane == 0) {
        wcnt[w][0] = wq0; wcnt[w][1] = wq1;
        wcnt[w][2] = wq2; wcnt[w][3] = wq3;
    }
    __syncthreads();
    if (t < 4) {                          // serial 16-wave scan per quarter
        int run = 0;
        for (int ww = 0; ww < 16; ww++) { wbase[ww][t] = run; run += wcnt[ww][t]; }
        qcnt[((s * 64 + g) << 2) + t] = run;
    }
    __syncthreads();
    const int rbase = (s * 64 + g) << 2;
#pragma unroll
    for (int r = 0; r < 8; r++) {
        int q = qv[r];
        packed[(size_t)(rbase + q) * QCAP + wbase[w][q] + pos[r]] = pk[r];
    }
}

// ---------------------------------------------------------------------------
// K2 (R23 form, R27: +2x manual unroll): agg2 — LDS fixed-point scatter-add.
// One block per (g = b&63 [XCD affinity], q = b>>6): 512-node quarter slab
// as int32 LDS accumulator (64KB). 4 threads/edge (8 dims each): gather
// x[src] (2 independent float4), 8 independent LDS atomicAdd — deep ILP
// per iteration. R26 POST-MORTEM (121us regression, reverted): lane-per-dim
// w/ conflict-free banks cut per-iteration ILP 8x and exposed the full
// pkv->gather dependent chain 256 times; conflicts were worth <=6us, ILP
// worth 88us. ESTABLISHED: keep >=8 independent memory ops in flight per
// iteration here; bank conflicts in this kernel are second-order.
// R27: process edge slots i and i+256 per iteration (2 pkv loads, 4 float4
// loads, 16 atomics in flight). Same term multiset, int adds commute ->
// agg bit-identical, replay-deterministic.
// Overflow: |sum| <= ~45*5*2^22 ~ 9.4e8 < 2^31.
// ---------------------------------------------------------------------------
__global__ __launch_bounds__(1024) void agg2_kernel(
    const float* __restrict__ x,
    const int* __restrict__ qcnt, const int* __restrict__ packed,
    float* __restrict__ agg)
{
    __shared__ int acc[512 * DD];        // 65536 B
    int b = blockIdx.x, t = threadIdx.x;
    int g = b & 63, q = b >> 6;
    for (int i = t; i < 512 * DD; i += 1024) acc[i] = 0;
    __syncthreads();

    const float SCALE = 4194304.0f;      // 2^22
    const float* xg = x + (size_t)g * NPG * DD;
    int sub   = t & 3;                   // dims sub*8 .. sub*8+7
    int ei0   = t >> 2;                  // 0..255
    int dbase = sub << 3;

    for (int s = 0; s < 4; s++) {
        int n = qcnt[((s * 64 + g) << 2) + q];
        const int* pb = packed + (size_t)(((s * 64 + g) << 2) + q) * QCAP;
        int i = ei0;
        for (; i + 256 < n; i += 512) {
            int pkvA = pb[i];
            int pkvB = pb[i + 256];
            int dlA  = pkvA & 511, slA = pkvA >> 9;
            int dlB  = pkvB & 511, slB = pkvB >> 9;
            const float4* xpA = (const float4*)(xg + slA * DD + dbase);
            const float4* xpB = (const float4*)(xg + slB * DD + dbase);
            float4 a0 = xpA[0];
            float4 a1 = xpA[1];
            float4 b0 = xpB[0];
            float4 b1 = xpB[1];
            int* arA = acc + (dlA << 5); int mA = dlA & 31;
            int* arB = acc + (dlB << 5); int mB = dlB & 31;
            atomicAdd(arA + ((dbase + 0) ^ mA), __float2int_rn(a0.x * SCALE));
            atomicAdd(arA + ((dbase + 1) ^ mA), __float2int_rn(a0.y * SCALE));
            atomicAdd(arA + ((dbase + 2) ^ mA), __float2int_rn(a0.z * SCALE));
            atomicAdd(arA + ((dbase + 3) ^ mA), __float2int_rn(a0.w * SCALE));
            atomicAdd(arA + ((dbase + 4) ^ mA), __float2int_rn(a1.x * SCALE));
            atomicAdd(arA + ((dbase + 5) ^ mA), __float2int_rn(a1.y * SCALE));
            atomicAdd(arA + ((dbase + 6) ^ mA), __float2int_rn(a1.z * SCALE));
            atomicAdd(arA + ((dbase + 7) ^ mA), __float2int_rn(a1.w * SCALE));
            atomicAdd(arB + ((dbase + 0) ^ mB), __float2int_rn(b0.x * SCALE));
            atomicAdd(arB + ((dbase + 1) ^ mB), __float2int_rn(b0.y * SCALE));
            atomicAdd(arB + ((dbase + 2) ^ mB), __float2int_rn(b0.z * SCALE));
            atomicAdd(arB + ((dbase + 3) ^ mB), __float2int_rn(b0.w * SCALE));
            atomicAdd(arB + ((dbase + 4) ^ mB), __float2int_rn(b1.x * SCALE));
            atomicAdd(arB + ((dbase + 5) ^ mB), __float2int_rn(b1.y * SCALE));
            atomicAdd(arB + ((dbase + 6) ^ mB), __float2int_rn(b1.z * SCALE));
            atomicAdd(arB + ((dbase + 7) ^ mB), __float2int_rn(b1.w * SCALE));
        }
        if (i < n) {
            int pkv = pb[i];
            int dl  = pkv & 511;
            int sl  = pkv >> 9;
            const float4* xp = (const float4*)(xg + sl * DD + dbase);
            float4 v0 = xp[0];
            float4 v1 = xp[1];
            int* ar = acc + (dl << 5);
            int  m  = dl & 31;
            atomicAdd(ar + ((dbase + 0) ^ m), __float2int_rn(v0.x * SCALE));
            atomicAdd(ar + ((dbase + 1) ^ m), __float2int_rn(v0.y * SCALE));
            atomicAdd(ar + ((dbase + 2) ^ m), __float2int_rn(v0.z * SCALE));
            atomicAdd(ar + ((dbase + 3) ^ m), __float2int_rn(v0.w * SCALE));
            atomicAdd(ar + ((dbase + 4) ^ m), __float2int_rn(v1.x * SCALE));
            atomicAdd(ar + ((dbase + 5) ^ m), __float2int_rn(v1.y * SCALE));
            atomicAdd(ar + ((dbase + 6) ^ m), __float2int_rn(v1.z * SCALE));
            atomicAdd(ar + ((dbase + 7) ^ m), __float2int_rn(v1.w * SCALE));
        }
    }
    __syncthreads();

    const float ISCALE = 2.38418579101562e-07f;  // 2^-22
    float* ao = agg + ((size_t)g * NPG + (size_t)q * 512) * DD;
    for (int i = t; i < 512 * DD; i += 1024) {   // coalesced stores, swz reads
        int row = i >> 5, d = i & 31;
        ao[i] = (float)acc[(row << 5) | (d ^ (row & 31))] * ISCALE;
    }
}

// ---------------------------------------------------------------------------
// K2b: per-node score = <x2, y2> / sqrt(32). fp32 W in LDS (ds_read_b128,
// wave-uniform address -> broadcast, conflict-free). R=2 node-pairing
// (i, i+NN/2) + 2-way d-split — FINAL form, ~36us. Measured tree: beats
// bf16-W (R13), global-W (R7), launch-bounds caps (R10), float2 SLP (R16),
// forced v_pk_fma_f32 (R20: VALU saved but ds_read latency exposed, 36->44),
// scalar-W one-node-per-thread (R25: 128-float live set -> spill/remat
// churn, 36->115us REGRESSION, reverted). ESTABLISHED: this register
// blocking (4-float acc blocks, 2 threads/node) is the sweet spot; score
// must stay fp32-accurate; only summation-order changes are safe.
// ---------------------------------------------------------------------------
__global__ __launch_bounds__(256) void score_kernel(
    const float* __restrict__ x, const float* __restrict__ agg,
    const float* __restrict__ Wr1, const float* __restrict__ Wl1, const float* __restrict__ b1,
    const float* __restrict__ Wr2, const float* __restrict__ Wl2, const float* __restrict__ b2,
    float* __restrict__ score)
{
    __shared__ float4 sWr1[DD*DD/4], sWl1[DD*DD/4], sWr2[DD*DD/4], sWl2[DD*DD/4];
    __shared__ float sb1[DD], sb2[DD];
    __shared__ float2 part[128];
    {
        int t = threadIdx.x;             // 256 threads, 256 float4 per matrix
        sWr1[t] = ((const float4*)Wr1)[t];
        sWl1[t] = ((const float4*)Wl1)[t];
        sWr2[t] = ((const float4*)Wr2)[t];
        sWl2[t] = ((const float4*)Wl2)[t];
        if (t < DD) { sb1[t] = b1[t]; sb2[t] = b2[t]; }
    }
    __syncthreads();

    int lane = threadIdx.x & 127;
    int half = threadIdx.x >> 7;                 // 0: d0 0-3, 1: d0 4-7
    int i0 = blockIdx.x * 128 + lane;            // 0 .. NN/2-1
    int i1 = i0 + NN/2;                          // second dense stream

    float xv0[DD], av0[DD], xv1[DD], av1[DD];
    {
        const float4* xp0 = (const float4*)(x + (long long)i0 * DD);
        const float4* ap0 = (const float4*)(agg + (long long)i0 * DD);
        const float4* xp1 = (const float4*)(x + (long long)i1 * DD);
        const float4* ap1 = (const float4*)(agg + (long long)i1 * DD);
#pragma unroll
        for (int q = 0; q < 8; q++) {
            float4 v0 = xp0[q]; xv0[4*q]=v0.x; xv0[4*q+1]=v0.y; xv0[4*q+2]=v0.z; xv0[4*q+3]=v0.w;
            float4 w0 = ap0[q]; av0[4*q]=w0.x; av0[4*q+1]=w0.y; av0[4*q+2]=w0.z; av0[4*q+3]=w0.w;
            float4 v1 = xp1[q]; xv1[4*q]=v1.x; xv1[4*q+1]=v1.y; xv1[4*q+2]=v1.z; xv1[4*q+3]=v1.w;
            float4 w1 = ap1[q]; av1[4*q]=w1.x; av1[4*q+1]=w1.y; av1[4*q+2]=w1.z; av1[4*q+3]=w1.w;
        }
    }

    float sc0 = 0.f, sc1 = 0.f;
    int dbase = half * 4;
    for (int dd = 0; dd < 4; dd++) {             // this thread's 4 d0-blocks
        int d0 = dbase + dd;
        float a0[4], q0[4], a1[4], q1[4];
#pragma unroll
        for (int j = 0; j < 4; j++) {
            a0[j] = sb1[4*d0+j]; q0[j] = sb2[4*d0+j];
            a1[j] = sb1[4*d0+j]; q1[j] = sb2[4*d0+j];
        }
#pragma unroll
        for (int k = 0; k < DD; k++) {
            float4 wr1 = sWr1[k*8 + d0];
            float4 wl1 = sWl1[k*8 + d0];
            float4 wr2 = sWr2[k*8 + d0];
            float4 wl2 = sWl2[k*8 + d0];
            const float* r1 = &wr1.x; const float* l1 = &wl1.x;
            const float* r2 = &wr2.x; const float* l2 = &wl2.x;
            float xk0 = xv0[k], ak0 = av0[k];
            float xk1 = xv1[k], ak1 = av1[k];
#pragma unroll
            for (int j = 0; j < 4; j++) {
                a0[j] += xk0 * r1[j];   // per-d chain order == round 8
                a0[j] += ak0 * l1[j];
                q0[j] += xk0 * r2[j];
                q0[j] += ak0 * l2[j];
                a1[j] += xk1 * r1[j];
                a1[j] += ak1 * l1[j];
                q1[j] += xk1 * r2[j];
                q1[j] += ak1 * l2[j];
            }
        }
#pragma unroll
        for (int j = 0; j < 4; j++) { sc0 += a0[j] * q0[j]; sc1 += a1[j] * q1[j]; }
    }

    if (half) { part[lane].x = sc0; part[lane].y = sc1; }
    __syncthreads();
    if (!half) {
        float2 p = part[lane];
        score[i0] = (sc0 + p.x) * 0.17677669529663687f;   // 1/sqrt(32)
        score[i1] = (sc1 + p.y) * 0.17677669529663687f;
    }
}

// ---------------------------------------------------------------------------
// K3 (R24): per-graph top-K bitonic sort, register/shfl accelerated.
// Mapping: wave w, lane ln owns elements e0 = w*128+ln, e1 = e0+64.
// j<=32 intra-wave (__shfl_xor); j==64 intra-thread; only j>=128 uses LDS.
// 15 __syncthreads total (was 66). Unique keys -> total order -> ANY correct
// sort gives bit-identical output -> deterministic. Also initializes new_idx
// for ALL nodes (kept -> new label, dropped -> -1).
// ---------------------------------------------------------------------------
__device__ __forceinline__ u64 shfl_xor_u64(u64 v, int j) {
    u32 lo = (u32)v, hi = (u32)(v >> 32);
    lo = (u32)__shfl_xor((int)lo, j, 64);
    hi = (u32)__shfl_xor((int)hi, j, 64);
    return ((u64)hi << 32) | lo;
}

__device__ __forceinline__ void reg_step(u64& v, int e, int j, int k) {
    u64 vp = shfl_xor_u64(v, j);
    bool upper   = (e & j) != 0;
    bool asc     = (e & k) == 0;
    bool takemax = (upper == asc);
    bool gt      = v > vp;
    v = (gt == takemax) ? v : vp;
}

__global__ __launch_bounds__(1024) void topk_kernel(
    const float* __restrict__ score,
    int* __restrict__ perm_int, int* __restrict__ new_idx,
    float* __restrict__ out_perm,
    float* __restrict__ out_batch,
    float* __restrict__ out_score)
{
    __shared__ u64 keys[NPG];
    int b = blockIdx.x;
    int t = threadIdx.x;
    const float* s = score + (long long)b * NPG;
    int w = t >> 6, ln = t & 63;
    int e0 = w * 128 + ln, e1 = e0 + 64;

    u64 k0, k1;
    {
        u32 u = __float_as_uint(s[e0]);
        u32 h = (u & 0x80000000u) ? u : ~(u | 0x80000000u);
        k0 = ((u64)h << 32) | (u32)e0;
        u = __float_as_uint(s[e1]);
        h = (u & 0x80000000u) ? u : ~(u | 0x80000000u);
        k1 = ((u64)h << 32) | (u32)e1;
    }

    // levels k = 2..128: fully in-register, no barriers
    for (int k = 2; k <= 128; k <<= 1) {
        for (int j = k >> 1; j >= 1; j >>= 1) {
            if (j == 64) {
                bool asc = (e0 & k) == 0;
                u64 mx = (k0 > k1) ? k0 : k1;
                u64 mn = (k0 > k1) ? k1 : k0;
                k0 = asc ? mn : mx;
                k1 = asc ? mx : mn;
            } else {
                reg_step(k0, e0, j, k);
                reg_step(k1, e1, j, k);
            }
        }
    }

    // levels k = 256..2048: LDS for j>=128, registers below
    for (int k = 256; k <= NPG; k <<= 1) {
        keys[e0] = k0; keys[e1] = k1;
        __syncthreads();
        for (int j = k >> 1; j >= 128; j >>= 1) {
            int i = ((t & ~(j - 1)) << 1) | (t & (j - 1));
            int l = i | j;
            u64 a = keys[i], c = keys[l];
            bool up = ((i & k) == 0);
            if ((a > c) == up) { keys[i] = c; keys[l] = a; }
            __syncthreads();
        }
        k0 = keys[e0]; k1 = keys[e1];
        for (int j = 64; j >= 1; j >>= 1) {
            if (j == 64) {
                bool asc = (e0 & k) == 0;
                u64 mx = (k0 > k1) ? k0 : k1;
                u64 mn = (k0 > k1) ? k1 : k0;
                k0 = asc ? mn : mx;
                k1 = asc ? mx : mn;
            } else {
                reg_step(k0, e0, j, k);
                reg_step(k1, e1, j, k);
            }
        }
    }

    keys[e0] = k0; keys[e1] = k1;
    __syncthreads();

    // kept half: ranks 0..KK-1 (thread t owns rank t)
    u64 kk = keys[t];
    int idx = (int)(u32)(kk & 0xFFFFFFFFu);
    int g = b * NPG + idx;
    int o = b * KK + t;
    perm_int[o] = g;
    new_idx[g] = o;
    out_perm[o]  = (float)g;
    out_batch[o] = (float)b;
    out_score[o] = s[idx];

    // dropped half: ranks KK..NPG-1 -> new_idx = -1 (replaces memset)
    u64 kd = keys[t + KK];
    int idxd = (int)(u32)(kd & 0xFFFFFFFFu);
    new_idx[b * NPG + idxd] = -1;
}

// ---------------------------------------------------------------------------
// K4: x5 = x[g] + score[g] * (x[g]@Wr3 + agg[g]@Wl3 + b3), kept nodes only.
// d-split: two threads per node; fp32 W in LDS. NOTE: must complete before
// edge_kernel (agg aliases out_ei) — keep launches serial.
// ---------------------------------------------------------------------------
__global__ __launch_bounds__(256) void x5_kernel(
    const float* __restrict__ x, const float* __restrict__ agg,
    const float* __restrict__ Wr3, const float* __restrict__ Wl3, const float* __restrict__ b3,
    const int* __restrict__ perm_int, const float* __restrict__ score,
    float* __restrict__ out_x5)
{
    __shared__ float4 sWr[DD*DD/4], sWl[DD*DD/4];
    __shared__ float sb[DD];
    {
        int t = threadIdx.x;
        sWr[t] = ((const float4*)Wr3)[t];
        sWl[t] = ((const float4*)Wl3)[t];
        if (t < DD) sb[t] = b3[t];
    }
    __syncthreads();

    int lane = threadIdx.x & 127;
    int half = threadIdx.x >> 7;
    int i = blockIdx.x * 128 + lane;             // 0 .. NB*KK-1 (grid 512)
    int g = perm_int[i];
    float sc = score[g];

    float xv[DD], av[DD];
    {
        const float4* xp = (const float4*)(x + (long long)g * DD);
        const float4* ap = (const float4*)(agg + (long long)g * DD);
#pragma unroll
        for (int q = 0; q < 8; q++) {
            float4 v = xp[q]; xv[4*q]=v.x; xv[4*q+1]=v.y; xv[4*q+2]=v.z; xv[4*q+3]=v.w;
            float4 w = ap[q]; av[4*q]=w.x; av[4*q+1]=w.y; av[4*q+2]=w.z; av[4*q+3]=w.w;
        }
    }

    float* outp = out_x5 + (long long)i * DD;
    int dbase = half * 4;
    for (int dd = 0; dd < 4; dd++) {
        int d0 = dbase + dd;
        float a[4];
#pragma unroll
        for (int j = 0; j < 4; j++) a[j] = sb[4*d0+j];
#pragma unroll
        for (int k = 0; k < DD; k++) {
            float xk = xv[k], ak = av[k];
            float4 wr = sWr[k*8 + d0];
            float4 wl = sWl[k*8 + d0];
            const float* rp = &wr.x; const float* lp = &wl.x;
#pragma unroll
            for (int j = 0; j < 4; j++) {
                a[j] += xk * rp[j];
                a[j] += ak * lp[j];
            }
        }
#pragma unroll
        for (int j = 0; j < 4; j++) outp[4*d0+j] = xv[4*d0+j] + sc * a[j];
    }
}

// ---------------------------------------------------------------------------
// K5: filter_adj — relabel edges, mask dropped. 4 edges/thread, vectorized.
// Runs last; overwrites the agg (out_ei) scratch.
// ---------------------------------------------------------------------------
__global__ __launch_bounds__(256) void edge_kernel(
    const int* __restrict__ src, const int* __restrict__ dst,
    const float* __restrict__ edge_attr,
    const int* __restrict__ new_idx,
    float* __restrict__ out_ei,    // [2*EE]
    float* __restrict__ out_attr)  // [EE]
{
    int e = (blockIdx.x * 256 + threadIdx.x) * 4;
    if (e >= EE) return;
    int4 s4 = *(const int4*)(src + e);
    int4 d4 = *(const int4*)(dst + e);
    float4 at = *(const float4*)(edge_attr + e);

    int ns[4] = { new_idx[s4.x], new_idx[s4.y], new_idx[s4.z], new_idx[s4.w] };
    int nd[4] = { new_idx[d4.x], new_idx[d4.y], new_idx[d4.z], new_idx[d4.w] };
    float av[4] = { at.x, at.y, at.z, at.w };

    float4 os, od, oa;
    float* osp = &os.x; float* odp = &od.x; float* oap = &oa.x;
#pragma unroll
    for (int j = 0; j < 4; j++) {
        bool valid = (ns[j] >= 0) && (nd[j] >= 0);
        osp[j] = (float)(valid ? ns[j] : -1);
        odp[j] = (float)(valid ? nd[j] : -1);
        oap[j] = valid ? av[j] : 0.f;
    }
    *(float4*)(out_ei + e)      = os;
    *(float4*)(out_ei + EE + e) = od;
    *(float4*)(out_attr + e)    = oa;
}

// ---------------------------------------------------------------------------
extern "C" void kernel_launch(void* const* d_in, const int* in_sizes, int n_in,
                              void* d_out, int out_size, void* d_ws, size_t ws_size,
                              hipStream_t stream)
{
    const float* x     = (const float*)d_in[0];         // fp32 [N, D]
    const int*   src   = (const int*)d_in[1];           // edge_index[0]
    const int*   dst   = ((const int*)d_in[1]) + EE;    // edge_index[1]
    const float* eattr = (const float*)d_in[2];         // fp32 [E]
    // d_in[3] = batch (implied: node g belongs to graph g/NPG)
    const float* Wr1 = (const float*)d_in[4];
    const float* Wl1 = (const float*)d_in[5];
    const float* b1  = (const float*)d_in[6];
    const float* Wr2 = (const float*)d_in[7];
    const float* Wl2 = (const float*)d_in[8];
    const float* b2  = (const float*)d_in[9];
    const float* Wr3 = (const float*)d_in[10];
    const float* Wl3 = (const float*)d_in[11];
    const float* b3  = (const float*)d_in[12];

    // ---- workspace layout (~11.8 MiB)
    char* ws = (char*)d_ws;
    float* score    = (float*)(ws + 0);                                   // NN*4
    int*   perm_int = (int*)  (ws + (size_t)NN*4);                        // NB*KK*4
    int*   new_idx  = (int*)  (ws + (size_t)NN*4 + (size_t)NB*KK*4);      // NN*4
    int*   qcnt     = (int*)  (ws + (size_t)NN*8 + (size_t)NB*KK*4);      // 1024*4
    int*   packed   = (int*)  (ws + (size_t)NN*8 + (size_t)NB*KK*4 + 4096); // 1024*QCAP*4

    // ---- output layout: ONE flat fp32 buffer, reference return order
    float* out = (float*)d_out;
    float* out_x5    = out;                       // NB*KK*DD = 2097152
    float* out_ei    = out + (size_t)NB*KK*DD;    // 2*EE     = 4194304
    float* out_attr  = out_ei + (size_t)2*EE;     // EE       = 2097152
    float* out_batch = out_attr + (size_t)EE;     // NB*KK
    float* out_perm  = out_batch + (size_t)NB*KK; // NB*KK
    float* out_score = out_perm + (size_t)NB*KK;  // NB*KK

    // Scratch aliasing into dead output region (edge_kernel runs last):
    //   agg = NN*DD fp32 == out_ei region (exact fit)
    float* agg = out_ei;

    qscatter_kernel<<<256, 1024, 0, stream>>>(src, dst, qcnt, packed);

    agg2_kernel<<<256, 1024, 0, stream>>>(x, qcnt, packed, agg);

    score_kernel<<<NN/256, 256, 0, stream>>>(x, agg, Wr1, Wl1, b1, Wr2, Wl2, b2, score);

    topk_kernel<<<NB, 1024, 0, stream>>>(score, perm_int, new_idx,
                                         out_perm, out_batch, out_score);

    x5_kernel<<<(NB*KK)/128, 256, 0, stream>>>(x, agg, Wr3, Wl3, b3,
                                               perm_int, score, out_x5);

    edge_kernel<<<(EE/4)/256, 256, 0, stream>>>(src, dst, eattr, new_idx, out_ei, out_attr);
}